// Round 1
// baseline (1504.125 us; speedup 1.0000x reference)
//
#include <hip/hip_runtime.h>
#include <math.h>

#define L_DIM 128
#define E_DIM 768
#define BK 32
#define NCHUNK (E_DIM / BK)   // 24

// One block per batch (B*K = 1024). 256 threads.
// Phase A (per chunk): stage ctx/ent rows -> LDS [k][l] transposed, fused
//   norm^2 and w0-dot accumulation from registers (input read from HBM once).
// Phase B (per chunk): 128x128 fp32 outer-product GEMM, 8x8 per thread.
// Then: argmax_m dot(c_l, e_m)*inv_en[m]  (== cosine argmax), tiny MLP, block sum.
__global__ __launch_bounds__(256, 3) void som_mlp_kernel(
    const float* __restrict__ ctx,
    const float* __restrict__ w0, const float* __restrict__ b0,
    const float* __restrict__ w1, const float* __restrict__ b1,
    const float* __restrict__ w2, const float* __restrict__ b2,
    const float* __restrict__ w3, const float* __restrict__ b3,
    const float* __restrict__ w4, const float* __restrict__ b4,
    const float* __restrict__ w5, const float* __restrict__ b5,
    const float* __restrict__ w6, const float* __restrict__ b6,
    float* __restrict__ out)
{
    __shared__ float ctile[BK][L_DIM];
    __shared__ float etile[BK][L_DIM];
    __shared__ float invn[2 * L_DIM];   // [0:128] 1/|c_l|, [128:256] 1/|e_m|
    __shared__ float Af[L_DIM][5];      // ctx_n . w0[:, :768]
    __shared__ float Bf[L_DIM][5];      // ent_n . w0[:, 768:]
    __shared__ float psum[2];

    const int t   = threadIdx.x;
    const int blk = blockIdx.x;
    const int mat = t >> 7;         // 0 = context, 1 = entity (wave-uniform)
    const int l   = t & 127;
    const int matu = __builtin_amdgcn_readfirstlane(mat);
    const int ty  = t >> 4;         // 0..15
    const int tx  = t & 15;         // 0..15

    const float4* rowp = (const float4*)(ctx + ((size_t)(blk * 2 + mat) * L_DIM + l) * E_DIM);
    const float* w0h = w0 + matu * 768;   // uniform -> scalar loads

    float (*mytile)[L_DIM] = mat ? etile : ctile;

    float nrm = 0.f;
    float dots[5] = {0.f, 0.f, 0.f, 0.f, 0.f};
    float acc[8][8];
    #pragma unroll
    for (int i = 0; i < 8; i++)
        #pragma unroll
        for (int j = 0; j < 8; j++) acc[i][j] = 0.f;

    float4 pf[8];
    #pragma unroll
    for (int q = 0; q < 8; q++) pf[q] = rowp[q];

    #pragma unroll 1
    for (int c = 0; c < NCHUNK; c++) {
        const float* vf = (const float*)pf;
        // stage to LDS (transposed) + fused norm/w0-dot accumulation
        #pragma unroll
        for (int k = 0; k < BK; k++) {
            float v = vf[k];
            mytile[k][l] = v;
            nrm = fmaf(v, v, nrm);
        }
        #pragma unroll
        for (int j = 0; j < 5; j++) {
            const float* wr = w0h + j * 1536 + c * BK;   // uniform -> s_load
            float d = dots[j];
            #pragma unroll
            for (int k = 0; k < BK; k++) d = fmaf(vf[k], wr[k], d);
            dots[j] = d;
        }
        __syncthreads();
        // prefetch next chunk (hidden under GEMM)
        if (c + 1 < NCHUNK) {
            #pragma unroll
            for (int q = 0; q < 8; q++) pf[q] = rowp[(c + 1) * 8 + q];
        }
        // 8x8 per-thread outer-product GEMM; rows {4ty..,64+4ty..}, cols {4tx..,64+4tx..}
        #pragma unroll 8
        for (int k = 0; k < BK; k++) {
            float4 a0  = *(const float4*)&ctile[k][ty * 4];
            float4 a1  = *(const float4*)&ctile[k][64 + ty * 4];
            float4 b0v = *(const float4*)&etile[k][tx * 4];
            float4 b1v = *(const float4*)&etile[k][64 + tx * 4];
            float av[8] = {a0.x, a0.y, a0.z, a0.w, a1.x, a1.y, a1.z, a1.w};
            float bv[8] = {b0v.x, b0v.y, b0v.z, b0v.w, b1v.x, b1v.y, b1v.z, b1v.w};
            #pragma unroll
            for (int i = 0; i < 8; i++)
                #pragma unroll
                for (int j = 0; j < 8; j++)
                    acc[i][j] = fmaf(av[i], bv[j], acc[i][j]);
        }
        __syncthreads();
    }

    // finalize norms + first-layer partials
    {
        float inv = 1.0f / sqrtf(nrm);
        invn[t] = inv;                       // t == mat*128 + l
        float* dst = mat ? &Bf[l][0] : &Af[l][0];
        #pragma unroll
        for (int j = 0; j < 5; j++) dst[j] = dots[j] * inv;
    }
    __syncthreads();

    // ---- argmax: scale this thread's 8x8 dots by inv_en[col], local argmax per row ----
    float* maxv = (float*)ctile;             // 128*17 floats (overlay, tiles dead)
    int*   maxi = (int*)etile;               // 128*17 ints
    float ien[8];
    #pragma unroll
    for (int j = 0; j < 8; j++)
        ien[j] = invn[128 + tx * 4 + (j & 3) + 64 * (j >> 2)];
    #pragma unroll
    for (int i = 0; i < 8; i++) {
        int r = ty * 4 + (i & 3) + 64 * (i >> 2);
        float bestv = -1e30f; int bestc = 0x7fffffff;
        #pragma unroll
        for (int j = 0; j < 8; j++) {
            int cc = tx * 4 + (j & 3) + 64 * (j >> 2);
            float s = acc[i][j] * ien[j];
            if (s > bestv || (s == bestv && cc < bestc)) { bestv = s; bestc = cc; }
        }
        maxv[r * 17 + tx] = bestv;
        maxi[r * 17 + tx] = bestc;
    }
    __syncthreads();

    if (t < 128) {
        // cross-thread argmax reduce, np.argmax first-index tie-break
        float bestv = maxv[t * 17];
        int   besti = maxi[t * 17];
        #pragma unroll
        for (int x = 1; x < 16; x++) {
            float v  = maxv[t * 17 + x];
            int   i2 = maxi[t * 17 + x];
            if (v > bestv || (v == bestv && i2 < besti)) { bestv = v; besti = i2; }
        }
        // tiny MLP chain (weights read via scalar loads)
        float x0[5];
        #pragma unroll
        for (int j = 0; j < 5; j++)
            x0[j] = tanhf(Af[t][j] + Bf[besti][j] + b0[j]);
        float y0 = b1[0], y1 = b1[1];
        #pragma unroll
        for (int j = 0; j < 5; j++) {
            y0 = fmaf(w1[j],     x0[j], y0);
            y1 = fmaf(w1[5 + j], x0[j], y1);
        }
        y0 = tanhf(y0); y1 = tanhf(y1);
        float z = tanhf(fmaf(w2[0], y0, fmaf(w2[1], y1, b2[0])));
        z = tanhf(fmaf(w3[0], z, b3[0]));
        z = tanhf(fmaf(w4[0], z, b4[0]));
        z = tanhf(fmaf(w5[0], z, b5[0]));
        z = fmaf(w6[0], z, b6[0]);
        // block reduction over 128 rows (2 full waves)
        #pragma unroll
        for (int off = 32; off > 0; off >>= 1) z += __shfl_down(z, off);
        if ((t & 63) == 0) psum[t >> 6] = z;
    }
    __syncthreads();
    if (t == 0) out[blk] = psum[0] + psum[1];
}

extern "C" void kernel_launch(void* const* d_in, const int* in_sizes, int n_in,
                              void* d_out, int out_size, void* d_ws, size_t ws_size,
                              hipStream_t stream) {
    (void)in_sizes; (void)n_in; (void)d_ws; (void)ws_size; (void)out_size;
    const float* ctx = (const float*)d_in[0];
    som_mlp_kernel<<<dim3(1024), dim3(256), 0, stream>>>(
        ctx,
        (const float*)d_in[1],  (const float*)d_in[2],
        (const float*)d_in[3],  (const float*)d_in[4],
        (const float*)d_in[5],  (const float*)d_in[6],
        (const float*)d_in[7],  (const float*)d_in[8],
        (const float*)d_in[9],  (const float*)d_in[10],
        (const float*)d_in[11], (const float*)d_in[12],
        (const float*)d_in[13], (const float*)d_in[14],
        (float*)d_out);
}